// Round 15
// baseline (68.005 us; speedup 1.0000x reference)
//
#include <hip/hip_runtime.h>
#include <hip/hip_bf16.h>

// ANI-1 per-species MLP, v15: BARRIER-FREE — one wave owns 16 molecules
// end-to-end (all 160/128/96 outputs of every layer for its rows).
// Evidence: v5/v9/v11 (3 schedules) all pin at ~43us with no pipe >30% busy;
// v14 cut barriers 12->6 and VALU 25->18% yet REGRESSED -> the invariant is
// 8-wave lockstep barrier phasing. Here: zero __syncthreads in the MLP.
// Block = 1 atom (grid 512), 8 waves; wave w: mols w*16..+15. All LDS is
// per-wave slices (wave-synchronous, in-order DS). 16 independent waves/CU
// mix phases: HBM stream / L2 B-loads / MFMA / VALU epilogues co-schedule.
// LDS 77.8KB -> 2 blocks/CU; waves_per_eu(4,4) -> 128-VGPR budget.

typedef float f32x4 __attribute__((ext_vector_type(4)));
typedef short s16x8 __attribute__((ext_vector_type(8)));

#define NMOL   128
#define NATOM  512
#define AEV    384

#define XLD    36               // bf16 ld of per-wave X K-tile [16][36]
#define XBUF   576              // ushorts per X buffer (16*36)
#define ASL    2176             // ushorts per wave region-A slice (Y1 16*136)
#define BSL    2688             // ushorts per wave region-B slice (Y0 16*168)
#define Y0LD   168
#define Y1LD   136
#define Y2LD   104

// Wp element offsets (bf16 units)
#define PL0    61440            // 160*384
#define PL1    20480            // 128*160
#define PL2    12288            // 96*128
#define BASE0  0
#define BASE1  245760           // 4*PL0
#define BASE2  327680           // BASE1 + 4*PL1
#define WP_BYTE_OFF 262144      // partial buffer (512*128*4) first in d_ws

__device__ __forceinline__ ushort f2bf(float f) {   // RTN-even
    uint u = __float_as_uint(f);
    return (ushort)((u + 0x7fffu + ((u >> 16) & 1u)) >> 16);
}
__device__ __forceinline__ float bf2f(ushort h) {
    return __uint_as_float(((uint)h) << 16);
}
__device__ __forceinline__ float celu_f(float v) {
    return fmaxf(v, 0.0f) + fminf(0.1f * (__expf(10.0f * v) - 1.0f), 0.0f);
}
__device__ __forceinline__ uint pk2bf(float x, float y) {   // v_cvt_pk_bf16_f32
    __hip_bfloat162 h2;
    h2.x = __float2bfloat16(x);
    h2.y = __float2bfloat16(y);
    return *(uint*)&h2;
}

// ---- prep: W0..W2 fp32 -> bf16 in MFMA-B-fragment order, 8 elems/thread ----
__global__ __launch_bounds__(256) void prep_kernel(
    const float* __restrict__ W0, const float* __restrict__ W1,
    const float* __restrict__ W2, ushort* __restrict__ Wp)
{
    const int idx = blockIdx.x * 256 + threadIdx.x;   // grid = 47104 (x8 elems)
    int n, k0, KS;
    size_t base;
    const float* src;
    if (idx < 30720) {                        // L0: [4][160][384]
        const int s = idx / 7680, r = idx % 7680;
        n = r / 48; k0 = (r % 48) * 8; KS = 12;
        src = W0 + (size_t)idx * 8;
        base = BASE0 + (size_t)s * PL0;
    } else if (idx < 40960) {                 // L1: [4][128][160]
        const int i2 = idx - 30720;
        const int s = i2 / 2560, r = i2 % 2560;
        n = r / 20; k0 = (r % 20) * 8; KS = 5;
        src = W1 + (size_t)i2 * 8;
        base = BASE1 + (size_t)s * PL1;
    } else {                                  // L2: [4][96][128]
        const int i2 = idx - 40960;
        const int s = i2 / 1536, r = i2 % 1536;
        n = r / 16; k0 = (r % 16) * 8; KS = 4;
        src = W2 + (size_t)i2 * 8;
        base = BASE2 + (size_t)s * PL2;
    }
    const float4 v0 = *(const float4*)(src);
    const float4 v1 = *(const float4*)(src + 4);
    const size_t fo = (size_t)((((n >> 4) * KS + (k0 >> 5)) * 64
                                + ((k0 & 31) >> 3) * 16 + (n & 15)) * 8);
    uint4 w;
    w.x = pk2bf(v0.x, v0.y);
    w.y = pk2bf(v0.z, v0.w);
    w.z = pk2bf(v1.x, v1.y);
    w.w = pk2bf(v1.z, v1.w);
    *(uint4*)(Wp + base + fo) = w;
}

__global__ __attribute__((amdgpu_flat_work_group_size(512, 512),
                          amdgpu_waves_per_eu(4, 4)))
void ani_mfma_kernel(
    const float* __restrict__ aev, const int* __restrict__ species,
    const ushort* __restrict__ Wp,
    const float* __restrict__ b0, const float* __restrict__ b1,
    const float* __restrict__ b2,
    const float* __restrict__ W3, const float* __restrict__ b3,
    float* __restrict__ partial)
{
    // Per-wave slices, no cross-wave access anywhere:
    //  region A slice (2176 ush): X dbuf 2x[16][36] (first 1152) -> Y1 [16][136]
    //  region B slice (2688 ush): Y0 [16][168] -> Y2 [16][104]
    __shared__ __align__(16) ushort smemA[8 * ASL];   // 34816 B
    __shared__ __align__(16) ushort smemB[8 * BSL];   // 43008 B

    const int a    = blockIdx.x;        // atom
    const int tid  = threadIdx.x;
    const int lane = tid & 63;
    const int wid  = tid >> 6;          // wave owns mols wid*16..+15
    const int mol0 = wid * 16;

    const int s = species[a];
    const ushort* Bh0 = Wp + BASE0 + (size_t)s * PL0;
    const ushort* Bh1 = Wp + BASE1 + (size_t)s * PL1;
    const ushort* Bh2 = Wp + BASE2 + (size_t)s * PL2;
    const float* b0s = b0 + s * 160;
    const float* b1s = b1 + s * 128;
    const float* b2s = b2 + s * 96;
    const float* w3s = W3 + s * 96;
    const float  bb3 = b3[s];

    ushort* Xw  = smemA + wid * ASL;    // X dbuf (first 1152 ushorts)
    ushort* Y1w = smemA + wid * ASL;    // [16][136], over dead X (wave-local)
    ushort* Y0w = smemB + wid * BSL;    // [16][168]
    ushort* Y2w = smemB + wid * BSL;    // [16][104], over dead Y0 (wave-local)

    const f32x4 zero = {0.f, 0.f, 0.f, 0.f};

    // staging map: lane -> (row = lane>>2, chunk c = lane&3 of 8 fp32)
    const int srow = lane >> 2;
    const int sc   = lane & 3;
    const float* sp = aev + ((size_t)(mol0 + srow) * NATOM + a) * AEV + sc * 8;

    // stage K-tile t into buf b: 2 float4 -> 4 cvt_pk -> 1 ds_write_b128
    auto stage = [&](int t, int b) {
        const float4 v0 = *(const float4*)(sp + t * 32);
        const float4 v1 = *(const float4*)(sp + t * 32 + 4);
        uint4 w;
        w.x = pk2bf(v0.x, v0.y);
        w.y = pk2bf(v0.z, v0.w);
        w.z = pk2bf(v1.x, v1.y);
        w.w = pk2bf(v1.z, v1.w);
        *(uint4*)(Xw + b * XBUF + srow * XLD + sc * 8) = w;
    };

    // ---- L0: 384 -> 160, wave-private dbuf, NO barriers ----
    f32x4 acc0[10];
    #pragma unroll
    for (int nf = 0; nf < 10; ++nf) acc0[nf] = zero;

    stage(0, 0);
    {
        const ushort* arow = Xw + (lane & 15) * XLD + (lane >> 4) * 8;
        #pragma unroll
        for (int gks = 0; gks < 12; ++gks) {
            if (gks < 11) stage(gks + 1, (gks + 1) & 1);
            const s16x8 ah = *(const s16x8*)(arow + (gks & 1) * XBUF);
            #pragma unroll
            for (int nf = 0; nf < 10; ++nf) {
                const s16x8 bh = *(const s16x8*)(
                    Bh0 + ((size_t)(nf * 12 + gks) * 64 + lane) * 8);
                acc0[nf] = __builtin_amdgcn_mfma_f32_16x16x32_bf16(ah, bh, acc0[nf], 0, 0, 0);
            }
        }
    }
    // L0 epilogue -> Y0w (wave-local rows 0..15)
    #pragma unroll
    for (int nf = 0; nf < 10; ++nf) {
        const int n = nf * 16 + (lane & 15);
        const float bv = b0s[n];
        #pragma unroll
        for (int r = 0; r < 4; ++r) {
            const int row = (lane >> 4) * 4 + r;
            Y0w[row * Y0LD + n] = f2bf(celu_f(acc0[nf][r] + bv));
        }
    }

    // ---- L1: 160 -> 128 (all wave-local; in-order DS makes this safe) ----
    f32x4 acc1[8];
    #pragma unroll
    for (int nf = 0; nf < 8; ++nf) acc1[nf] = zero;
    {
        const ushort* arow = Y0w + (lane & 15) * Y0LD + (lane >> 4) * 8;
        #pragma unroll
        for (int ks = 0; ks < 5; ++ks) {
            const s16x8 ah = *(const s16x8*)(arow + ks * 32);
            #pragma unroll
            for (int nf = 0; nf < 8; ++nf) {
                const s16x8 bh = *(const s16x8*)(
                    Bh1 + ((size_t)(nf * 5 + ks) * 64 + lane) * 8);
                acc1[nf] = __builtin_amdgcn_mfma_f32_16x16x32_bf16(ah, bh, acc1[nf], 0, 0, 0);
            }
        }
    }
    // L1 epilogue -> Y1w (over dead X, wave-local)
    #pragma unroll
    for (int nf = 0; nf < 8; ++nf) {
        const int n = nf * 16 + (lane & 15);
        const float bv = b1s[n];
        #pragma unroll
        for (int r = 0; r < 4; ++r) {
            const int row = (lane >> 4) * 4 + r;
            Y1w[row * Y1LD + n] = f2bf(celu_f(acc1[nf][r] + bv));
        }
    }

    // ---- L2: 128 -> 96 ----
    f32x4 acc2[6];
    #pragma unroll
    for (int nf = 0; nf < 6; ++nf) acc2[nf] = zero;
    {
        const ushort* arow = Y1w + (lane & 15) * Y1LD + (lane >> 4) * 8;
        #pragma unroll
        for (int ks = 0; ks < 4; ++ks) {
            const s16x8 ah = *(const s16x8*)(arow + ks * 32);
            #pragma unroll
            for (int nf = 0; nf < 6; ++nf) {
                const s16x8 bh = *(const s16x8*)(
                    Bh2 + ((size_t)(nf * 4 + ks) * 64 + lane) * 8);
                acc2[nf] = __builtin_amdgcn_mfma_f32_16x16x32_bf16(ah, bh, acc2[nf], 0, 0, 0);
            }
        }
    }
    // L2 epilogue -> Y2w (over dead Y0, wave-local)
    #pragma unroll
    for (int nf = 0; nf < 6; ++nf) {
        const int n = nf * 16 + (lane & 15);
        const float bv = b2s[n];
        #pragma unroll
        for (int r = 0; r < 4; ++r) {
            const int row = (lane >> 4) * 4 + r;
            Y2w[row * Y2LD + n] = f2bf(celu_f(acc2[nf][r] + bv));
        }
    }

    // ---- L3: 96 -> 1 (wave-local; 4 lanes per row, shfl reduce) ----
    {
        const int row = lane >> 2;          // 0..15
        const int q   = lane & 3;           // 24 inputs each
        float accv = 0.f;
        #pragma unroll
        for (int ii = 0; ii < 24; ++ii) {
            const int i = q * 24 + ii;
            accv = fmaf(w3s[i], bf2f(Y2w[row * Y2LD + i]), accv);
        }
        accv += __shfl_xor(accv, 1);
        accv += __shfl_xor(accv, 2);
        if (q == 0)
            partial[(size_t)a * NMOL + mol0 + row] = accv + bb3;
    }
}

__global__ __launch_bounds__(256) void reduce_kernel(
    const float* __restrict__ partial, float* __restrict__ out)
{
    __shared__ float red[256];
    const int m = blockIdx.x;       // molecule
    const int t = threadIdx.x;
    float sv = partial[(size_t)t * NMOL + m] + partial[(size_t)(t + 256) * NMOL + m];
    red[t] = sv;
    __syncthreads();
    #pragma unroll
    for (int w = 128; w > 0; w >>= 1) {
        if (t < w) red[t] += red[t + w];
        __syncthreads();
    }
    if (t == 0) out[m] = red[0];
}

extern "C" void kernel_launch(void* const* d_in, const int* in_sizes, int n_in,
                              void* d_out, int out_size, void* d_ws, size_t ws_size,
                              hipStream_t stream) {
    const float* aev     = (const float*)d_in[0];
    const int*   species = (const int*)  d_in[1];
    const float* W0 = (const float*)d_in[2];
    const float* b0 = (const float*)d_in[3];
    const float* W1 = (const float*)d_in[4];
    const float* b1 = (const float*)d_in[5];
    const float* W2 = (const float*)d_in[6];
    const float* b2 = (const float*)d_in[7];
    const float* W3 = (const float*)d_in[8];
    const float* b3 = (const float*)d_in[9];
    float* out     = (float*)d_out;
    float* partial = (float*)d_ws;                               // 256 KiB
    ushort* Wp     = (ushort*)((char*)d_ws + WP_BYTE_OFF);       // ~0.75 MiB

    prep_kernel<<<184, 256, 0, stream>>>(W0, W1, W2, Wp);
    ani_mfma_kernel<<<NATOM, 512, 0, stream>>>(aev, species, Wp,
                                               b0, b1, b2, W3, b3, partial);
    reduce_kernel<<<NMOL, 256, 0, stream>>>(partial, out);
}

// Round 16
// 67.627 us; speedup vs baseline: 1.0056x; 1.0056x over previous
//
#include <hip/hip_runtime.h>
#include <hip/hip_bf16.h>

// ANI-1 per-species MLP, v15: BARRIER-FREE — one wave owns 16 molecules
// end-to-end (all 160/128/96 outputs of every layer for its rows).
// Evidence: v5/v9/v11 (3 schedules) all pin at ~43us with no pipe >30% busy;
// v14 cut barriers 12->6 and VALU 25->18% yet REGRESSED -> the invariant is
// 8-wave lockstep barrier phasing. Here: zero __syncthreads in the MLP.
// Block = 1 atom (grid 512), 8 waves; wave w: mols w*16..+15. All LDS is
// per-wave slices (wave-synchronous, in-order DS). 16 independent waves/CU
// mix phases: HBM stream / L2 B-loads / MFMA / VALU epilogues co-schedule.
// LDS 77.8KB -> 2 blocks/CU; waves_per_eu(4,4) -> 128-VGPR budget.

typedef float f32x4 __attribute__((ext_vector_type(4)));
typedef short s16x8 __attribute__((ext_vector_type(8)));

#define NMOL   128
#define NATOM  512
#define AEV    384

#define XLD    36               // bf16 ld of per-wave X K-tile [16][36]
#define XBUF   576              // ushorts per X buffer (16*36)
#define ASL    2176             // ushorts per wave region-A slice (Y1 16*136)
#define BSL    2688             // ushorts per wave region-B slice (Y0 16*168)
#define Y0LD   168
#define Y1LD   136
#define Y2LD   104

// Wp element offsets (bf16 units)
#define PL0    61440            // 160*384
#define PL1    20480            // 128*160
#define PL2    12288            // 96*128
#define BASE0  0
#define BASE1  245760           // 4*PL0
#define BASE2  327680           // BASE1 + 4*PL1
#define WP_BYTE_OFF 262144      // partial buffer (512*128*4) first in d_ws

__device__ __forceinline__ ushort f2bf(float f) {   // RTN-even
    uint u = __float_as_uint(f);
    return (ushort)((u + 0x7fffu + ((u >> 16) & 1u)) >> 16);
}
__device__ __forceinline__ float bf2f(ushort h) {
    return __uint_as_float(((uint)h) << 16);
}
__device__ __forceinline__ float celu_f(float v) {
    return fmaxf(v, 0.0f) + fminf(0.1f * (__expf(10.0f * v) - 1.0f), 0.0f);
}
__device__ __forceinline__ uint pk2bf(float x, float y) {   // v_cvt_pk_bf16_f32
    __hip_bfloat162 h2;
    h2.x = __float2bfloat16(x);
    h2.y = __float2bfloat16(y);
    return *(uint*)&h2;
}

// ---- prep: W0..W2 fp32 -> bf16 in MFMA-B-fragment order, 8 elems/thread ----
__global__ __launch_bounds__(256) void prep_kernel(
    const float* __restrict__ W0, const float* __restrict__ W1,
    const float* __restrict__ W2, ushort* __restrict__ Wp)
{
    const int idx = blockIdx.x * 256 + threadIdx.x;   // grid = 47104 (x8 elems)
    int n, k0, KS;
    size_t base;
    const float* src;
    if (idx < 30720) {                        // L0: [4][160][384]
        const int s = idx / 7680, r = idx % 7680;
        n = r / 48; k0 = (r % 48) * 8; KS = 12;
        src = W0 + (size_t)idx * 8;
        base = BASE0 + (size_t)s * PL0;
    } else if (idx < 40960) {                 // L1: [4][128][160]
        const int i2 = idx - 30720;
        const int s = i2 / 2560, r = i2 % 2560;
        n = r / 20; k0 = (r % 20) * 8; KS = 5;
        src = W1 + (size_t)i2 * 8;
        base = BASE1 + (size_t)s * PL1;
    } else {                                  // L2: [4][96][128]
        const int i2 = idx - 40960;
        const int s = i2 / 1536, r = i2 % 1536;
        n = r / 16; k0 = (r % 16) * 8; KS = 4;
        src = W2 + (size_t)i2 * 8;
        base = BASE2 + (size_t)s * PL2;
    }
    const float4 v0 = *(const float4*)(src);
    const float4 v1 = *(const float4*)(src + 4);
    const size_t fo = (size_t)((((n >> 4) * KS + (k0 >> 5)) * 64
                                + ((k0 & 31) >> 3) * 16 + (n & 15)) * 8);
    uint4 w;
    w.x = pk2bf(v0.x, v0.y);
    w.y = pk2bf(v0.z, v0.w);
    w.z = pk2bf(v1.x, v1.y);
    w.w = pk2bf(v1.z, v1.w);
    *(uint4*)(Wp + base + fo) = w;
}

__global__ __attribute__((amdgpu_flat_work_group_size(512, 512),
                          amdgpu_waves_per_eu(4, 4)))
void ani_mfma_kernel(
    const float* __restrict__ aev, const int* __restrict__ species,
    const ushort* __restrict__ Wp,
    const float* __restrict__ b0, const float* __restrict__ b1,
    const float* __restrict__ b2,
    const float* __restrict__ W3, const float* __restrict__ b3,
    float* __restrict__ partial)
{
    // Per-wave slices, no cross-wave access anywhere:
    //  region A slice (2176 ush): X dbuf 2x[16][36] (first 1152) -> Y1 [16][136]
    //  region B slice (2688 ush): Y0 [16][168] -> Y2 [16][104]
    __shared__ __align__(16) ushort smemA[8 * ASL];   // 34816 B
    __shared__ __align__(16) ushort smemB[8 * BSL];   // 43008 B

    const int a    = blockIdx.x;        // atom
    const int tid  = threadIdx.x;
    const int lane = tid & 63;
    const int wid  = tid >> 6;          // wave owns mols wid*16..+15
    const int mol0 = wid * 16;

    const int s = species[a];
    const ushort* Bh0 = Wp + BASE0 + (size_t)s * PL0;
    const ushort* Bh1 = Wp + BASE1 + (size_t)s * PL1;
    const ushort* Bh2 = Wp + BASE2 + (size_t)s * PL2;
    const float* b0s = b0 + s * 160;
    const float* b1s = b1 + s * 128;
    const float* b2s = b2 + s * 96;
    const float* w3s = W3 + s * 96;
    const float  bb3 = b3[s];

    ushort* Xw  = smemA + wid * ASL;    // X dbuf (first 1152 ushorts)
    ushort* Y1w = smemA + wid * ASL;    // [16][136], over dead X (wave-local)
    ushort* Y0w = smemB + wid * BSL;    // [16][168]
    ushort* Y2w = smemB + wid * BSL;    // [16][104], over dead Y0 (wave-local)

    const f32x4 zero = {0.f, 0.f, 0.f, 0.f};

    // staging map: lane -> (row = lane>>2, chunk c = lane&3 of 8 fp32)
    const int srow = lane >> 2;
    const int sc   = lane & 3;
    const float* sp = aev + ((size_t)(mol0 + srow) * NATOM + a) * AEV + sc * 8;

    // stage K-tile t into buf b: 2 float4 -> 4 cvt_pk -> 1 ds_write_b128
    auto stage = [&](int t, int b) {
        const float4 v0 = *(const float4*)(sp + t * 32);
        const float4 v1 = *(const float4*)(sp + t * 32 + 4);
        uint4 w;
        w.x = pk2bf(v0.x, v0.y);
        w.y = pk2bf(v0.z, v0.w);
        w.z = pk2bf(v1.x, v1.y);
        w.w = pk2bf(v1.z, v1.w);
        *(uint4*)(Xw + b * XBUF + srow * XLD + sc * 8) = w;
    };

    // ---- L0: 384 -> 160, wave-private dbuf, NO barriers ----
    f32x4 acc0[10];
    #pragma unroll
    for (int nf = 0; nf < 10; ++nf) acc0[nf] = zero;

    stage(0, 0);
    {
        const ushort* arow = Xw + (lane & 15) * XLD + (lane >> 4) * 8;
        #pragma unroll
        for (int gks = 0; gks < 12; ++gks) {
            if (gks < 11) stage(gks + 1, (gks + 1) & 1);
            const s16x8 ah = *(const s16x8*)(arow + (gks & 1) * XBUF);
            #pragma unroll
            for (int nf = 0; nf < 10; ++nf) {
                const s16x8 bh = *(const s16x8*)(
                    Bh0 + ((size_t)(nf * 12 + gks) * 64 + lane) * 8);
                acc0[nf] = __builtin_amdgcn_mfma_f32_16x16x32_bf16(ah, bh, acc0[nf], 0, 0, 0);
            }
        }
    }
    // L0 epilogue -> Y0w (wave-local rows 0..15)
    #pragma unroll
    for (int nf = 0; nf < 10; ++nf) {
        const int n = nf * 16 + (lane & 15);
        const float bv = b0s[n];
        #pragma unroll
        for (int r = 0; r < 4; ++r) {
            const int row = (lane >> 4) * 4 + r;
            Y0w[row * Y0LD + n] = f2bf(celu_f(acc0[nf][r] + bv));
        }
    }

    // ---- L1: 160 -> 128 (all wave-local; in-order DS makes this safe) ----
    f32x4 acc1[8];
    #pragma unroll
    for (int nf = 0; nf < 8; ++nf) acc1[nf] = zero;
    {
        const ushort* arow = Y0w + (lane & 15) * Y0LD + (lane >> 4) * 8;
        #pragma unroll
        for (int ks = 0; ks < 5; ++ks) {
            const s16x8 ah = *(const s16x8*)(arow + ks * 32);
            #pragma unroll
            for (int nf = 0; nf < 8; ++nf) {
                const s16x8 bh = *(const s16x8*)(
                    Bh1 + ((size_t)(nf * 5 + ks) * 64 + lane) * 8);
                acc1[nf] = __builtin_amdgcn_mfma_f32_16x16x32_bf16(ah, bh, acc1[nf], 0, 0, 0);
            }
        }
    }
    // L1 epilogue -> Y1w (over dead X, wave-local)
    #pragma unroll
    for (int nf = 0; nf < 8; ++nf) {
        const int n = nf * 16 + (lane & 15);
        const float bv = b1s[n];
        #pragma unroll
        for (int r = 0; r < 4; ++r) {
            const int row = (lane >> 4) * 4 + r;
            Y1w[row * Y1LD + n] = f2bf(celu_f(acc1[nf][r] + bv));
        }
    }

    // ---- L2: 128 -> 96 ----
    f32x4 acc2[6];
    #pragma unroll
    for (int nf = 0; nf < 6; ++nf) acc2[nf] = zero;
    {
        const ushort* arow = Y1w + (lane & 15) * Y1LD + (lane >> 4) * 8;
        #pragma unroll
        for (int ks = 0; ks < 4; ++ks) {
            const s16x8 ah = *(const s16x8*)(arow + ks * 32);
            #pragma unroll
            for (int nf = 0; nf < 6; ++nf) {
                const s16x8 bh = *(const s16x8*)(
                    Bh2 + ((size_t)(nf * 4 + ks) * 64 + lane) * 8);
                acc2[nf] = __builtin_amdgcn_mfma_f32_16x16x32_bf16(ah, bh, acc2[nf], 0, 0, 0);
            }
        }
    }
    // L2 epilogue -> Y2w (over dead Y0, wave-local)
    #pragma unroll
    for (int nf = 0; nf < 6; ++nf) {
        const int n = nf * 16 + (lane & 15);
        const float bv = b2s[n];
        #pragma unroll
        for (int r = 0; r < 4; ++r) {
            const int row = (lane >> 4) * 4 + r;
            Y2w[row * Y2LD + n] = f2bf(celu_f(acc2[nf][r] + bv));
        }
    }

    // ---- L3: 96 -> 1 (wave-local; 4 lanes per row, shfl reduce) ----
    {
        const int row = lane >> 2;          // 0..15
        const int q   = lane & 3;           // 24 inputs each
        float accv = 0.f;
        #pragma unroll
        for (int ii = 0; ii < 24; ++ii) {
            const int i = q * 24 + ii;
            accv = fmaf(w3s[i], bf2f(Y2w[row * Y2LD + i]), accv);
        }
        accv += __shfl_xor(accv, 1);
        accv += __shfl_xor(accv, 2);
        if (q == 0)
            partial[(size_t)a * NMOL + mol0 + row] = accv + bb3;
    }
}

__global__ __launch_bounds__(256) void reduce_kernel(
    const float* __restrict__ partial, float* __restrict__ out)
{
    __shared__ float red[256];
    const int m = blockIdx.x;       // molecule
    const int t = threadIdx.x;
    float sv = partial[(size_t)t * NMOL + m] + partial[(size_t)(t + 256) * NMOL + m];
    red[t] = sv;
    __syncthreads();
    #pragma unroll
    for (int w = 128; w > 0; w >>= 1) {
        if (t < w) red[t] += red[t + w];
        __syncthreads();
    }
    if (t == 0) out[m] = red[0];
}

extern "C" void kernel_launch(void* const* d_in, const int* in_sizes, int n_in,
                              void* d_out, int out_size, void* d_ws, size_t ws_size,
                              hipStream_t stream) {
    const float* aev     = (const float*)d_in[0];
    const int*   species = (const int*)  d_in[1];
    const float* W0 = (const float*)d_in[2];
    const float* b0 = (const float*)d_in[3];
    const float* W1 = (const float*)d_in[4];
    const float* b1 = (const float*)d_in[5];
    const float* W2 = (const float*)d_in[6];
    const float* b2 = (const float*)d_in[7];
    const float* W3 = (const float*)d_in[8];
    const float* b3 = (const float*)d_in[9];
    float* out     = (float*)d_out;
    float* partial = (float*)d_ws;                               // 256 KiB
    ushort* Wp     = (ushort*)((char*)d_ws + WP_BYTE_OFF);       // ~0.75 MiB

    prep_kernel<<<184, 256, 0, stream>>>(W0, W1, W2, Wp);
    ani_mfma_kernel<<<NATOM, 512, 0, stream>>>(aev, species, Wp,
                                               b0, b1, b2, W3, b3, partial);
    reduce_kernel<<<NMOL, 256, 0, stream>>>(partial, out);
}

// Round 17
// 44.123 us; speedup vs baseline: 1.5413x; 1.5327x over previous
//
#include <hip/hip_runtime.h>
#include <hip/hip_bf16.h>

// ANI-1 per-species MLP, v17: v11 (glds, 4 blocks/CU — tied-best 43us) with
// L0 phase count HALVED: K=64 tiles -> 6 phases x 12 MFMA/wave (was 12 x 6).
// Evidence: v15 (no barriers) regressed 57% -> lockstep theory dead; v5/v9/
// v11 tie at 43 sharing {B amortized, staging overlapped, >=2 blocks/CU};
// v11's residual cost = per-phase fixed overhead over only 6 MFMAs.
// glds swizzle for 16-chunk rows: chunk j of row r at (j&8)|((j&7)^(r&7));
// rows 0-7 cover all 32 banks (2-way across 16 rows = free).
// LDS packed to exactly 40960B -> 4 blocks/CU = 160KiB. 64-VGPR discipline.

typedef float f32x4 __attribute__((ext_vector_type(4)));
typedef short s16x8 __attribute__((ext_vector_type(8)));

#define NMOL   128
#define NATOM  512
#define AEV    384
#define MT     64               // molecules per block
#define Y0LD   168
#define Y1LD   136
#define Y2LD   104
#define Y1_OFF 10752            // ushort offset (byte 21504)
#define RED_OFF 19456           // ushort offset (byte 38912)

// Wp element offsets (bf16 units)
#define PL0    61440            // 160*384
#define PL1    20480            // 128*160
#define PL2    12288            // 96*128
#define BASE0  0
#define BASE1  245760           // 4*PL0
#define BASE2  327680           // BASE1 + 4*PL1
#define WP_BYTE_OFF 262144      // partial buffer (512*128*4) first in d_ws

typedef const __attribute__((address_space(1))) void* gas_ptr;
typedef __attribute__((address_space(3))) void* las_ptr;

__device__ __forceinline__ ushort f2bf(float f) {   // RTN-even
    uint u = __float_as_uint(f);
    return (ushort)((u + 0x7fffu + ((u >> 16) & 1u)) >> 16);
}
__device__ __forceinline__ float bf2f(ushort h) {
    return __uint_as_float(((uint)h) << 16);
}
__device__ __forceinline__ float celu_f(float v) {
    return fmaxf(v, 0.0f) + fminf(0.1f * (__expf(10.0f * v) - 1.0f), 0.0f);
}
__device__ __forceinline__ uint pk2bf(float x, float y) {   // v_cvt_pk_bf16_f32
    __hip_bfloat162 h2;
    h2.x = __float2bfloat16(x);
    h2.y = __float2bfloat16(y);
    return *(uint*)&h2;
}

// ---- prep: W0..W2 fp32 -> bf16 in MFMA-B-fragment order, 8 elems/thread ----
__global__ __launch_bounds__(256) void prep_kernel(
    const float* __restrict__ W0, const float* __restrict__ W1,
    const float* __restrict__ W2, ushort* __restrict__ Wp)
{
    const int idx = blockIdx.x * 256 + threadIdx.x;   // grid = 47104 (x8 elems)
    int n, k0, KS;
    size_t base;
    const float* src;
    if (idx < 30720) {                        // L0: [4][160][384]
        const int s = idx / 7680, r = idx % 7680;
        n = r / 48; k0 = (r % 48) * 8; KS = 12;
        src = W0 + (size_t)idx * 8;
        base = BASE0 + (size_t)s * PL0;
    } else if (idx < 40960) {                 // L1: [4][128][160]
        const int i2 = idx - 30720;
        const int s = i2 / 2560, r = i2 % 2560;
        n = r / 20; k0 = (r % 20) * 8; KS = 5;
        src = W1 + (size_t)i2 * 8;
        base = BASE1 + (size_t)s * PL1;
    } else {                                  // L2: [4][96][128]
        const int i2 = idx - 40960;
        const int s = i2 / 1536, r = i2 % 1536;
        n = r / 16; k0 = (r % 16) * 8; KS = 4;
        src = W2 + (size_t)i2 * 8;
        base = BASE2 + (size_t)s * PL2;
    }
    const float4 v0 = *(const float4*)(src);
    const float4 v1 = *(const float4*)(src + 4);
    const size_t fo = (size_t)((((n >> 4) * KS + (k0 >> 5)) * 64
                                + ((k0 & 31) >> 3) * 16 + (n & 15)) * 8);
    uint4 w;
    w.x = pk2bf(v0.x, v0.y);
    w.y = pk2bf(v0.z, v0.w);
    w.z = pk2bf(v1.x, v1.y);
    w.w = pk2bf(v1.z, v1.w);
    *(uint4*)(Wp + base + fo) = w;
}

__global__ __attribute__((amdgpu_flat_work_group_size(512, 512),
                          amdgpu_waves_per_eu(8, 8)))
void ani_mfma_kernel(
    const float* __restrict__ aev, const int* __restrict__ species,
    const ushort* __restrict__ Wp,
    const float* __restrict__ b0, const float* __restrict__ b1,
    const float* __restrict__ b2,
    const float* __restrict__ W3, const float* __restrict__ b3,
    float* __restrict__ partial)
{
    // 40960 B, phase-aliased:
    //  L0:   X fp32 dbuf  [0..16384) and [16384..32768)
    //  post: Y0 [0..21504) -> Y1 [21504..38912) -> Y2 [0..13312)
    //  red   [38912..40960)
    __shared__ __align__(16) ushort smem[20480];

    const int bid  = blockIdx.x;
    const int a    = bid >> 1;          // atom
    const int half = bid & 1;           // molecule half
    const int tid  = threadIdx.x;
    const int lane = tid & 63;
    const int wid  = tid >> 6;
    const int mgrp = wid >> 2;          // 0..1 (32-row groups)
    const int ngrp = wid & 3;           // 0..3
    const bool has3 = (ngrp < 2);       // L0 nf=ngrp+8<10; L2 nf=ngrp+4<6

    const int s = species[a];
    const ushort* Bh0 = Wp + BASE0 + (size_t)s * PL0;
    const ushort* Bh1 = Wp + BASE1 + (size_t)s * PL1;
    const ushort* Bh2 = Wp + BASE2 + (size_t)s * PL2;
    const float* b0s = b0 + s * 160;
    const float* b1s = b1 + s * 128;
    const float* b2s = b2 + s * 96;
    const float* w3s = W3 + s * 96;
    const float  bb3 = b3[s];

    ushort* y0buf = smem;               // [64][168]
    ushort* y1buf = smem + Y1_OFF;      // [64][136]
    ushort* y2buf = smem;               // [64][104]

    // ---- glds source: wave stages rows wid*8..+7 of the 64-row X tile.
    // Tile t covers k = t*64..+63 (256 B/row = 16 chunks); two calls h=0,1.
    // Pre-swizzled source chunk for lane (mol8 = lane>>3, c7 = lane&7):
    //   j_src = h*8 + (c7 ^ mol8)  -> LDS slot (mol8, h, c7) holds that chunk.
    const int mol8 = lane >> 3;
    const int swz  = (lane & 7) ^ mol8;
    const char* gsrc = (const char*)(aev
        + ((size_t)(half * MT + wid * 8 + mol8) * NATOM + a) * AEV) + swz * 16;
    const int ldsbase = wid * 2048;     // wave's 2KB slice within an X buffer

    const f32x4 zero = {0.f, 0.f, 0.f, 0.f};
    f32x4 acc[2][3];
    #pragma unroll
    for (int mf = 0; mf < 2; ++mf)
        #pragma unroll
        for (int ti = 0; ti < 3; ++ti) acc[mf][ti] = zero;

    // ---- L0: 384 -> 160, 6 K-64 tiles, glds dbuf, 12 MFMA/wave/phase ----
    {
        const int r0 = mgrp * 32 + (lane & 15);   // fragment row (+ mf*16)
        const int c2 = (lane >> 4) * 2;           // chunk pair base within half

        // prologue: tile 0 -> buf 0
        __builtin_amdgcn_global_load_lds((gas_ptr)(gsrc),
            (las_ptr)((char*)smem + ldsbase), 16, 0, 0);
        __builtin_amdgcn_global_load_lds((gas_ptr)(gsrc + 128),
            (las_ptr)((char*)smem + ldsbase + 1024), 16, 0, 0);
        __syncthreads();

        #pragma unroll
        for (int t = 0; t < 6; ++t) {
            if (t < 5) {   // issue next tile into other buffer
                const char* g = gsrc + (t + 1) * 256;
                char* d = (char*)smem + ((t + 1) & 1) * 16384 + ldsbase;
                __builtin_amdgcn_global_load_lds((gas_ptr)(g),       (las_ptr)(d),        16, 0, 0);
                __builtin_amdgcn_global_load_lds((gas_ptr)(g + 128), (las_ptr)(d + 1024), 16, 0, 0);
            }
            const float* Xb = (const float*)((const char*)smem + (t & 1) * 16384);
            #pragma unroll
            for (int gs = 0; gs < 2; ++gs) {
                const int gks = t * 2 + gs;
                const s16x8 bh0 = *(const s16x8*)(
                    Bh0 + ((size_t)((ngrp    ) * 12 + gks) * 64 + lane) * 8);
                const s16x8 bh1 = *(const s16x8*)(
                    Bh0 + ((size_t)((ngrp + 4) * 12 + gks) * 64 + lane) * 8);
                s16x8 bh2;
                if (has3) bh2 = *(const s16x8*)(
                    Bh0 + ((size_t)((ngrp + 8) * 12 + gks) * 64 + lane) * 8);

                s16x8 ah[2];
                #pragma unroll
                for (int mf = 0; mf < 2; ++mf) {
                    const int r = r0 + mf * 16;
                    // fp32 offsets: slice (r>>3)*512, half gs*256, row (r&7)*32,
                    // chunk ((c2+b)^(r&7))*4
                    const float* rp = Xb + (r >> 3) * 512 + gs * 256 + (r & 7) * 32;
                    const f32x4 v0 = *(const f32x4*)(rp + (((c2    ) ^ (r & 7)) * 4));
                    const f32x4 v1 = *(const f32x4*)(rp + (((c2 + 1) ^ (r & 7)) * 4));
                    union { s16x8 v; uint u[4]; } rr;
                    rr.u[0] = pk2bf(v0.x, v0.y);
                    rr.u[1] = pk2bf(v0.z, v0.w);
                    rr.u[2] = pk2bf(v1.x, v1.y);
                    rr.u[3] = pk2bf(v1.z, v1.w);
                    ah[mf] = rr.v;
                }
                acc[0][0] = __builtin_amdgcn_mfma_f32_16x16x32_bf16(ah[0], bh0, acc[0][0], 0, 0, 0);
                acc[1][0] = __builtin_amdgcn_mfma_f32_16x16x32_bf16(ah[1], bh0, acc[1][0], 0, 0, 0);
                acc[0][1] = __builtin_amdgcn_mfma_f32_16x16x32_bf16(ah[0], bh1, acc[0][1], 0, 0, 0);
                acc[1][1] = __builtin_amdgcn_mfma_f32_16x16x32_bf16(ah[1], bh1, acc[1][1], 0, 0, 0);
                if (has3) {
                    acc[0][2] = __builtin_amdgcn_mfma_f32_16x16x32_bf16(ah[0], bh2, acc[0][2], 0, 0, 0);
                    acc[1][2] = __builtin_amdgcn_mfma_f32_16x16x32_bf16(ah[1], bh2, acc[1][2], 0, 0, 0);
                }
            }
            __syncthreads();    // publishes buf(t+1); last iter guards Y0 alias
        }
    }

    // ---- L0 epilogue -> Y0 [0..21504) ----
    #pragma unroll
    for (int ti = 0; ti < 3; ++ti) {
        if (ti < 2 || has3) {
            const int n = (ngrp + 4 * ti) * 16 + (lane & 15);
            const float bv = b0s[n];
            #pragma unroll
            for (int mf = 0; mf < 2; ++mf) {
                #pragma unroll
                for (int r = 0; r < 4; ++r) {
                    const int row = mgrp * 32 + mf * 16 + (lane >> 4) * 4 + r;
                    y0buf[row * Y0LD + n] = f2bf(celu_f(acc[mf][ti][r] + bv));
                }
            }
        }
    }
    __syncthreads();                    // Y0 published

    // ---- L1: 160 -> 128 (A from Y0; C -> Y1 @ +21504B) ----
    f32x4 acc1[2][2];
    #pragma unroll
    for (int mf = 0; mf < 2; ++mf) { acc1[mf][0] = zero; acc1[mf][1] = zero; }
    {
        const ushort* arow0 = y0buf + (mgrp * 32 + (lane & 15)) * Y0LD + (lane >> 4) * 8;
        #pragma unroll
        for (int ks = 0; ks < 5; ++ks) {
            s16x8 ah[2];
            ah[0] = *(const s16x8*)(arow0 + ks * 32);
            ah[1] = *(const s16x8*)(arow0 + 16 * Y0LD + ks * 32);
            const s16x8 bh0 = *(const s16x8*)(
                Bh1 + ((size_t)((ngrp    ) * 5 + ks) * 64 + lane) * 8);
            const s16x8 bh1 = *(const s16x8*)(
                Bh1 + ((size_t)((ngrp + 4) * 5 + ks) * 64 + lane) * 8);
            acc1[0][0] = __builtin_amdgcn_mfma_f32_16x16x32_bf16(ah[0], bh0, acc1[0][0], 0, 0, 0);
            acc1[1][0] = __builtin_amdgcn_mfma_f32_16x16x32_bf16(ah[1], bh0, acc1[1][0], 0, 0, 0);
            acc1[0][1] = __builtin_amdgcn_mfma_f32_16x16x32_bf16(ah[0], bh1, acc1[0][1], 0, 0, 0);
            acc1[1][1] = __builtin_amdgcn_mfma_f32_16x16x32_bf16(ah[1], bh1, acc1[1][1], 0, 0, 0);
        }
    }

    // ---- L1 epilogue -> Y1 ----
    #pragma unroll
    for (int t = 0; t < 2; ++t) {
        const int n = (ngrp + 4 * t) * 16 + (lane & 15);
        const float bv = b1s[n];
        #pragma unroll
        for (int mf = 0; mf < 2; ++mf) {
            #pragma unroll
            for (int r = 0; r < 4; ++r) {
                const int row = mgrp * 32 + mf * 16 + (lane >> 4) * 4 + r;
                y1buf[row * Y1LD + n] = f2bf(celu_f(acc1[mf][t][r] + bv));
            }
        }
    }
    __syncthreads();                    // Y1 published; Y0 dead

    // ---- L2: 128 -> 96 (A from Y1; C -> Y2 over dead Y0) ----
    f32x4 acc2[2][2];
    #pragma unroll
    for (int mf = 0; mf < 2; ++mf) { acc2[mf][0] = zero; acc2[mf][1] = zero; }
    {
        const ushort* arow0 = y1buf + (mgrp * 32 + (lane & 15)) * Y1LD + (lane >> 4) * 8;
        #pragma unroll
        for (int ks = 0; ks < 4; ++ks) {
            s16x8 ah[2];
            ah[0] = *(const s16x8*)(arow0 + ks * 32);
            ah[1] = *(const s16x8*)(arow0 + 16 * Y1LD + ks * 32);
            const s16x8 bh0 = *(const s16x8*)(
                Bh2 + ((size_t)((ngrp) * 4 + ks) * 64 + lane) * 8);
            acc2[0][0] = __builtin_amdgcn_mfma_f32_16x16x32_bf16(ah[0], bh0, acc2[0][0], 0, 0, 0);
            acc2[1][0] = __builtin_amdgcn_mfma_f32_16x16x32_bf16(ah[1], bh0, acc2[1][0], 0, 0, 0);
            if (has3) {
                const s16x8 bh1 = *(const s16x8*)(
                    Bh2 + ((size_t)((ngrp + 4) * 4 + ks) * 64 + lane) * 8);
                acc2[0][1] = __builtin_amdgcn_mfma_f32_16x16x32_bf16(ah[0], bh1, acc2[0][1], 0, 0, 0);
                acc2[1][1] = __builtin_amdgcn_mfma_f32_16x16x32_bf16(ah[1], bh1, acc2[1][1], 0, 0, 0);
            }
        }
    }

    // ---- L2 epilogue -> Y2 ----
    #pragma unroll
    for (int t = 0; t < 2; ++t) {
        if (t == 0 || has3) {
            const int n = (ngrp + 4 * t) * 16 + (lane & 15);   // < 96
            const float bv = b2s[n];
            #pragma unroll
            for (int mf = 0; mf < 2; ++mf) {
                #pragma unroll
                for (int r = 0; r < 4; ++r) {
                    const int row = mgrp * 32 + mf * 16 + (lane >> 4) * 4 + r;
                    y2buf[row * Y2LD + n] = f2bf(celu_f(acc2[mf][t][r] + bv));
                }
            }
        }
    }
    __syncthreads();                    // Y2 published; Y1 dead

    // ---- L3: 96 -> 1 (fp32 vector; red @ +38912B, disjoint from Y2) ----
    {
        float* red = (float*)(smem + RED_OFF);
        const int m = tid & (MT - 1);
        const int q = tid >> 6;       // 0..7, 12 inputs each
        float accv = 0.f;
        #pragma unroll
        for (int ii = 0; ii < 12; ++ii) {
            const int i = q * 12 + ii;
            accv = fmaf(w3s[i], bf2f(y2buf[m * Y2LD + i]), accv);
        }
        red[q * MT + m] = accv;
        __syncthreads();
        if (tid < MT) {
            float sm = bb3;
            #pragma unroll
            for (int qq = 0; qq < 8; ++qq) sm += red[qq * MT + tid];
            partial[(size_t)a * NMOL + half * MT + tid] = sm;
        }
    }
}

__global__ __launch_bounds__(256) void reduce_kernel(
    const float* __restrict__ partial, float* __restrict__ out)
{
    __shared__ float red[256];
    const int m = blockIdx.x;       // molecule
    const int t = threadIdx.x;
    float sv = partial[(size_t)t * NMOL + m] + partial[(size_t)(t + 256) * NMOL + m];
    red[t] = sv;
    __syncthreads();
    #pragma unroll
    for (int w = 128; w > 0; w >>= 1) {
        if (t < w) red[t] += red[t + w];
        __syncthreads();
    }
    if (t == 0) out[m] = red[0];
}

extern "C" void kernel_launch(void* const* d_in, const int* in_sizes, int n_in,
                              void* d_out, int out_size, void* d_ws, size_t ws_size,
                              hipStream_t stream) {
    const float* aev     = (const float*)d_in[0];
    const int*   species = (const int*)  d_in[1];
    const float* W0 = (const float*)d_in[2];
    const float* b0 = (const float*)d_in[3];
    const float* W1 = (const float*)d_in[4];
    const float* b1 = (const float*)d_in[5];
    const float* W2 = (const float*)d_in[6];
    const float* b2 = (const float*)d_in[7];
    const float* W3 = (const float*)d_in[8];
    const float* b3 = (const float*)d_in[9];
    float* out     = (float*)d_out;
    float* partial = (float*)d_ws;                               // 256 KiB
    ushort* Wp     = (ushort*)((char*)d_ws + WP_BYTE_OFF);       // ~0.75 MiB

    prep_kernel<<<184, 256, 0, stream>>>(W0, W1, W2, Wp);
    ani_mfma_kernel<<<NATOM * 2, 512, 0, stream>>>(aev, species, Wp,
                                                   b0, b1, b2, W3, b3, partial);
    reduce_kernel<<<NMOL, 256, 0, stream>>>(partial, out);
}